// Round 6
// baseline (4960.047 us; speedup 1.0000x reference)
//
#include <hip/hip_runtime.h>

#define NL    5
#define NN    100000
#define NE    200000
#define MPAD  100096       // 782 * 128
#define MTILES 782
#define K1    320          // EMB 300 padded
#define N1    640          // 600 padded
#define NR1   600          // real N1 cols
#define K2    640          // z1b row stride
#define K2E   608          // effective K for gemm2: cols 600-639 of z1 are exactly 0
#define N2    384          // 300 padded
#define NR2   300          // real N2 cols
#define BN_EPS 1e-5f
#define G1    (MTILES * 5) // gemm1 grid (5 col-tiles)
#define G2    (MTILES * 3) // gemm2 grid (3 col-tiles)
#define NB_SCAN 98         // (NN + 1023) / 1024

typedef __attribute__((ext_vector_type(8))) short   short8;
typedef __attribute__((ext_vector_type(4))) float   floatx4;

// exact hi/lo bf16 split: x == bf(hi) + bf(lo) + O(2^-17 |x|)
__device__ inline void splitbf(float x, unsigned short& hi, unsigned short& lo) {
    unsigned u = __float_as_uint(x);
    unsigned hb = u & 0xFFFF0000u;
    float lf = x - __uint_as_float(hb);     // exact (shares leading bits)
    hi = (unsigned short)(u >> 16);
    lo = (unsigned short)(__float_as_uint(lf) >> 16);
}
__device__ inline unsigned short f2bf(float f) {
    unsigned u = __float_as_uint(f);
    unsigned r = u + 0x7FFFu + ((u >> 16) & 1u);   // RNE
    return (unsigned short)(r >> 16);
}
__device__ inline float bf2f(unsigned short b) {
    return __uint_as_float(((unsigned)b) << 16);
}

// XCD-contiguous swizzle
__device__ inline void swz(int id, int G, int NC, int& row, int& col) {
    int q = G >> 3, r = G & 7;
    int x = id & 7, k = id >> 3;
    int w = x * q + (x < r ? x : r) + k;
    row = w / NC; col = w % NC;
}

// ---------------- weight prep: hi/lo planes, n-major, padded ----------------
__global__ void prep_w1(const float* __restrict__ W1,
                        unsigned short* __restrict__ Whi, unsigned short* __restrict__ Wlo) {
    int idx = blockIdx.x * blockDim.x + threadIdx.x;
    if (idx >= NL * N1 * K1) return;                // [l][n<640][k<320]
    int l = idx / (N1 * K1);
    int rem = idx % (N1 * K1);
    int n = rem / K1;
    int k = rem % K1;
    float v = (k < 300 && n < 600) ? W1[((long)l * 300 + k) * 600 + n] : 0.f;
    unsigned short hi, lo; splitbf(v, hi, lo);
    Whi[idx] = hi; Wlo[idx] = lo;
}

__global__ void prep_w2(const float* __restrict__ W2,
                        unsigned short* __restrict__ Whi, unsigned short* __restrict__ Wlo) {
    int idx = blockIdx.x * blockDim.x + threadIdx.x;
    if (idx >= NL * N2 * K2) return;                // [l][d<384][k<640]
    int l = idx / (N2 * K2);
    int rem = idx % (N2 * K2);
    int d = rem / K2;
    int k = rem % K2;
    float v = (d < 300 && k < 600) ? W2[((long)l * 600 + k) * 300 + d] : 0.f;
    unsigned short hi, lo; splitbf(v, hi, lo);
    Whi[idx] = hi; Wlo[idx] = lo;
}

__global__ void prep_vec(const float* __restrict__ b1, const float* __restrict__ g1, const float* __restrict__ be1,
                         const float* __restrict__ b2, const float* __restrict__ g2, const float* __restrict__ be2,
                         float* __restrict__ b1p, float* __restrict__ g1p, float* __restrict__ be1p,
                         float* __restrict__ b2p, float* __restrict__ g2p, float* __restrict__ be2p) {
    int idx = blockIdx.x * blockDim.x + threadIdx.x;
    if (idx < NL * N1) {
        int l = idx / N1, n = idx % N1;
        bool ok = (n < 600);
        b1p[idx]  = ok ? b1[l * 600 + n]  : 0.f;
        g1p[idx]  = ok ? g1[l * 600 + n]  : 0.f;
        be1p[idx] = ok ? be1[l * 600 + n] : 0.f;
    }
    if (idx < NL * N2) {
        int l = idx / N2, d = idx % N2;
        bool ok = (d < 300);
        b2p[idx]  = ok ? b2[l * 300 + d]  : 0.f;
        g2p[idx]  = ok ? g2[l * 300 + d]  : 0.f;
        be2p[idx] = ok ? be2[l * 300 + d] : 0.f;
    }
}

// ---------------- atom encoder ----------------
__global__ void atom_enc(const int* __restrict__ xf, const float* __restrict__ tab,
                         float* __restrict__ h) {
    int idx = blockIdx.x * blockDim.x + threadIdx.x;
    if (idx >= NN * 75) return;
    int n = idx / 75;
    int c = (idx % 75) * 4;
    float4 s = make_float4(0.f, 0.f, 0.f, 0.f);
#pragma unroll
    for (int f = 0; f < 9; f++) {
        int v = xf[n * 9 + f];
        const float4 t = *(const float4*)(tab + (long)(f * 119 + v) * 300 + c);
        s.x += t.x; s.y += t.y; s.z += t.z; s.w += t.w;
    }
    *(float4*)(h + (long)n * 300 + c) = s;
}

// ---------------- CSR build ----------------
__global__ void count_deg(const int* __restrict__ ei, int* __restrict__ deg) {
    int e = blockIdx.x * blockDim.x + threadIdx.x;
    if (e >= NE) return;
    atomicAdd(&deg[ei[NE + e]], 1);
}

__global__ void block_deg_sum(const int* __restrict__ deg, int* __restrict__ bsum) {
    __shared__ int tmp[1024];
    const int t = threadIdx.x;
    const int idx = blockIdx.x * 1024 + t;
    tmp[t] = (idx < NN) ? deg[idx] : 0;
    __syncthreads();
    for (int o = 512; o > 0; o >>= 1) {
        if (t < o) tmp[t] += tmp[t + o];
        __syncthreads();
    }
    if (t == 0) bsum[blockIdx.x] = tmp[0];
}

__global__ void scan_rowptr2(const int* __restrict__ deg, const int* __restrict__ bsum,
                             int* __restrict__ rowptr) {
    __shared__ int tmp[1024];
    __shared__ int sbase;
    const int b = blockIdx.x;
    const int t = threadIdx.x;
    tmp[t] = (t < b) ? bsum[t] : 0;          // NB_SCAN <= 1024
    __syncthreads();
    for (int o = 512; o > 0; o >>= 1) {
        if (t < o) tmp[t] += tmp[t + o];
        __syncthreads();
    }
    if (t == 0) sbase = tmp[0];
    __syncthreads();
    const int base = sbase;
    const int idx = b * 1024 + t;
    const int d = (idx < NN) ? deg[idx] : 0;
    tmp[t] = d;
    __syncthreads();
    for (int o = 1; o < 1024; o <<= 1) {
        int u = (t >= o) ? tmp[t - o] : 0;
        __syncthreads();
        tmp[t] += u;
        __syncthreads();
    }
    if (idx < NN) rowptr[idx] = base + tmp[t] - d;   // exclusive prefix
    if (idx == NN - 1) rowptr[NN] = base + tmp[t];   // total edge count
}

__global__ void fill_csr(const int* __restrict__ ei, const int* __restrict__ ea,
                         const int* __restrict__ rowptr, int* __restrict__ fillc,
                         int* __restrict__ csr_src, int* __restrict__ csr_att) {
    int e = blockIdx.x * blockDim.x + threadIdx.x;
    if (e >= NE) return;
    int dst = ei[NE + e];
    int pos = atomicAdd(&fillc[dst], 1);
    int slot = rowptr[dst] + pos;
    csr_src[slot] = ei[e];
    csr_att[slot] = ea[e * 3] | (ea[e * 3 + 1] << 3) | (ea[e * 3 + 2] << 6);
}

// ---- gather + GIN combine + exact split, BN2+ReLU of previous layer folded in.
__global__ void gather_zin(const float* __restrict__ hsrc,
                           const float* __restrict__ sc2v, const float* __restrict__ sh2v,
                           int use_bn,
                           const int* __restrict__ rowptr,
                           const int* __restrict__ csr_src, const int* __restrict__ csr_att,
                           const float* __restrict__ bond,
                           const float* __restrict__ eps, int l,
                           unsigned short* __restrict__ zin) {
    int idx = blockIdx.x * blockDim.x + threadIdx.x;
    if (idx >= NN * 80) return;
    int n = idx / 80;
    int c = (idx % 80) * 4;
    ushort4 hi4, lo4;
    if (c < 300) {
        float4 sc = make_float4(1.f, 1.f, 1.f, 1.f);
        float4 sh = make_float4(0.f, 0.f, 0.f, 0.f);
        if (use_bn) {
            sc = *(const float4*)(sc2v + c);
            sh = *(const float4*)(sh2v + c);
        }
        int p0 = rowptr[n], p1 = rowptr[n + 1];
        float4 s = make_float4(0.f, 0.f, 0.f, 0.f);
        for (int j = p0; j < p1; j++) {
            int src = csr_src[j];
            int att = csr_att[j];
            float4 hv = *(const float4*)(hsrc + (long)src * 300 + c);
            if (use_bn) {
                hv.x = fmaxf(hv.x * sc.x + sh.x, 0.f);
                hv.y = fmaxf(hv.y * sc.y + sh.y, 0.f);
                hv.z = fmaxf(hv.z * sc.z + sh.z, 0.f);
                hv.w = fmaxf(hv.w * sc.w + sh.w, 0.f);
            }
            const float4 t0 = *(const float4*)(bond + (0 * 6 + (att & 7)) * 300 + c);
            const float4 t1 = *(const float4*)(bond + (1 * 6 + ((att >> 3) & 7)) * 300 + c);
            const float4 t2 = *(const float4*)(bond + (2 * 6 + ((att >> 6) & 1)) * 300 + c);
            float m;
            m = hv.x + t0.x + t1.x + t2.x; s.x += (m > 0.f ? m : 0.f);
            m = hv.y + t0.y + t1.y + t2.y; s.y += (m > 0.f ? m : 0.f);
            m = hv.z + t0.z + t1.z + t2.z; s.z += (m > 0.f ? m : 0.f);
            m = hv.w + t0.w + t1.w + t2.w; s.w += (m > 0.f ? m : 0.f);
        }
        const float ep = 1.f + eps[l];
        float4 hn = *(const float4*)(hsrc + (long)n * 300 + c);
        if (use_bn) {
            hn.x = fmaxf(hn.x * sc.x + sh.x, 0.f);
            hn.y = fmaxf(hn.y * sc.y + sh.y, 0.f);
            hn.z = fmaxf(hn.z * sc.z + sh.z, 0.f);
            hn.w = fmaxf(hn.w * sc.w + sh.w, 0.f);
        }
        splitbf(ep * hn.x + s.x, hi4.x, lo4.x);
        splitbf(ep * hn.y + s.y, hi4.y, lo4.y);
        splitbf(ep * hn.z + s.z, hi4.z, lo4.z);
        splitbf(ep * hn.w + s.w, hi4.w, lo4.w);
    } else {
        hi4.x = hi4.y = hi4.z = hi4.w = 0;
        lo4.x = lo4.y = lo4.z = lo4.w = 0;
    }
    *(ushort4*)(zin + (long)n * 640 + c)       = hi4;
    *(ushort4*)(zin + (long)n * 640 + 320 + c) = lo4;
}

// LDS bank-conflict swizzle (rule 21: linear gload_lds dest + inverse-swizzled
// global SOURCE + swizzled READ). Physical 16B slot = logical slot ^ ((row>>1)&3).
// R5 lesson: 128x64 wave tile regressed (occupancy 3->2 blocks/CU dominated the
// LDS-BW gain) -> stay at 64x64 wave tile, 128^2 block, (256,4).
// Dead-column guards: all guards below are wave-uniform and loop-invariant;
// live-column arithmetic is BITWISE identical to the unguarded kernel.

// ---------------- GEMM1: z1 = zin @ W1 + b1 (split-exact, pre-split A) ----------------
__global__ __launch_bounds__(256, 4)
void gemm1_pre(const unsigned short* __restrict__ zin,
               const unsigned short* __restrict__ Whi, const unsigned short* __restrict__ Wlo,
               const float* __restrict__ bias, unsigned short* __restrict__ z1b,
               float* __restrict__ stat_sum, float* __restrict__ stat_sq) {
    __shared__ unsigned short Ah[128 * 32], Al[128 * 32];
    __shared__ unsigned short Bh[128 * 32], Bl[128 * 32];
    __shared__ float ssum[128], ssq[128];

    const int tid  = threadIdx.x;
    const int wave = tid >> 6;
    const int lane = tid & 63;
    int rowb, colb; swz(blockIdx.x, G1, 5, rowb, colb);
    const long row0 = (long)rowb * 128;
    const long col0 = (long)colb * 128;

    floatx4 acc[4][4];
#pragma unroll
    for (int mi = 0; mi < 4; mi++)
#pragma unroll
        for (int ni = 0; ni < 4; ni++)
            acc[mi][ni] = (floatx4){0.f, 0.f, 0.f, 0.f};

    const int sr  = lane >> 2;
    const int scb = (((lane & 3) ^ ((sr >> 1) & 3))) * 8;  // pre-swizzled source slot
    const int wm  = (wave >> 1) * 64;
    const int wn  = (wave & 1) * 64;
    const int fr  = lane & 15;
    const int q   = lane >> 4;
    const int qs  = (q ^ ((fr >> 1) & 3)) * 8;             // swizzled read slot
    // dead-col liveness (cols >= NR1 have W=0, bias=0 -> outputs are exactly 0;
    // z1 cols 600-607 ARE still computed (live group), cols 608-639 never read
    // downstream since gemm2 stops at K2E=608)
    bool nlive[4];
#pragma unroll
    for (int ni = 0; ni < 4; ni++) nlive[ni] = (int)col0 + wn + ni * 16 < NR1;

    for (int k0 = 0; k0 < K1; k0 += 32) {
#pragma unroll
        for (int i = 0; i < 2; i++) {
            int r = wave * 32 + i * 16;
            const unsigned short* gah = zin + (row0 + r + sr) * 640 + k0 + scb;
            __builtin_amdgcn_global_load_lds((const __attribute__((address_space(1))) void*)gah,
                                             (__attribute__((address_space(3))) void*)(Ah + r * 32), 16, 0, 0);
            __builtin_amdgcn_global_load_lds((const __attribute__((address_space(1))) void*)(gah + 320),
                                             (__attribute__((address_space(3))) void*)(Al + r * 32), 16, 0, 0);
            if ((int)col0 + r < NR1) {   // B rows beyond NR1 are never read
                const unsigned short* gbh = Whi + (col0 + r + sr) * (long)K1 + k0 + scb;
                const unsigned short* gbl = Wlo + (col0 + r + sr) * (long)K1 + k0 + scb;
                __builtin_amdgcn_global_load_lds((const __attribute__((address_space(1))) void*)gbh,
                                                 (__attribute__((address_space(3))) void*)(Bh + r * 32), 16, 0, 0);
                __builtin_amdgcn_global_load_lds((const __attribute__((address_space(1))) void*)gbl,
                                                 (__attribute__((address_space(3))) void*)(Bl + r * 32), 16, 0, 0);
            }
        }
        __syncthreads();
        short8 ah[4], alo[4], bh[4], blo[4];
#pragma unroll
        for (int mi = 0; mi < 4; mi++) {
            ah[mi]  = *(const short8*)(Ah + (wm + mi * 16 + fr) * 32 + qs);
            alo[mi] = *(const short8*)(Al + (wm + mi * 16 + fr) * 32 + qs);
        }
#pragma unroll
        for (int ni = 0; ni < 4; ni++) {
            if (nlive[ni]) {
                bh[ni]  = *(const short8*)(Bh + (wn + ni * 16 + fr) * 32 + qs);
                blo[ni] = *(const short8*)(Bl + (wn + ni * 16 + fr) * 32 + qs);
            }
        }
#pragma unroll
        for (int mi = 0; mi < 4; mi++)
#pragma unroll
            for (int ni = 0; ni < 4; ni++) {
                if (nlive[ni]) {
                    acc[mi][ni] = __builtin_amdgcn_mfma_f32_16x16x32_bf16(ah[mi],  bh[ni],  acc[mi][ni], 0, 0, 0);
                    acc[mi][ni] = __builtin_amdgcn_mfma_f32_16x16x32_bf16(alo[mi], bh[ni],  acc[mi][ni], 0, 0, 0);
                    acc[mi][ni] = __builtin_amdgcn_mfma_f32_16x16x32_bf16(ah[mi],  blo[ni], acc[mi][ni], 0, 0, 0);
                }
            }
        __syncthreads();
    }

    if (tid < 128) { ssum[tid] = 0.f; ssq[tid] = 0.f; }
    __syncthreads();
#pragma unroll
    for (int ni = 0; ni < 4; ni++) {
        if (!nlive[ni]) continue;   // dead cols: z1=0 never read (K2E), stats stay 0
        int cl = wn + ni * 16 + fr;
        long cg = col0 + cl;
        float bs = bias[cg];
        float psum = 0.f, psq = 0.f;
#pragma unroll
        for (int mi = 0; mi < 4; mi++) {
#pragma unroll
            for (int r = 0; r < 4; r++) {
                long rg = row0 + wm + mi * 16 + q * 4 + r;
                float v = acc[mi][ni][r] + bs;
                z1b[rg * N1 + cg] = f2bf(v);
                if (rg < NN) { psum += v; psq += v * v; }
            }
        }
        atomicAdd(&ssum[cl], psum);
        atomicAdd(&ssq[cl], psq);
    }
    __syncthreads();
    if (tid < 128) {
        atomicAdd(&stat_sum[col0 + tid], ssum[tid]);
        atomicAdd(&stat_sq[col0 + tid], ssq[tid]);
    }
}

// ---------------- GEMM2 fused: z2 = relu(BN(z1)) @ W2 + b2 ----------------
__global__ __launch_bounds__(256, 4)
void gemm2_fused(const unsigned short* __restrict__ z1b,
                 const float* __restrict__ scale, const float* __restrict__ shift,
                 const unsigned short* __restrict__ Whi, const unsigned short* __restrict__ Wlo,
                 const float* __restrict__ bias, float* __restrict__ z2f,
                 float* __restrict__ stat_sum, float* __restrict__ stat_sq) {
    __shared__ unsigned short Ah[128 * 32], Al[128 * 32];
    __shared__ unsigned short Bh[128 * 32], Bl[128 * 32];
    __shared__ float sSc[K2], sSh[K2];
    __shared__ float ssum[128], ssq[128];

    const int tid  = threadIdx.x;
    const int wave = tid >> 6;
    const int lane = tid & 63;
    int rowb, colb; swz(blockIdx.x, G2, 3, rowb, colb);
    const long row0 = (long)rowb * 128;
    const long col0 = (long)colb * 128;

    for (int i = tid; i < K2; i += 256) { sSc[i] = scale[i]; sSh[i] = shift[i]; }

    floatx4 acc[4][4];
#pragma unroll
    for (int mi = 0; mi < 4; mi++)
#pragma unroll
        for (int ni = 0; ni < 4; ni++)
            acc[mi][ni] = (floatx4){0.f, 0.f, 0.f, 0.f};

    const int sr  = lane >> 2;
    const int scb = (((lane & 3) ^ ((sr >> 1) & 3))) * 8;   // pre-swizzled source slot
    const int wm  = (wave >> 1) * 64;
    const int wn  = (wave & 1) * 64;
    const int fr  = lane & 15;
    const int q   = lane >> 4;
    const int qs  = (q ^ ((fr >> 1) & 3)) * 8;              // swizzled read slot
    const int arow = tid >> 1;
    const int acb  = (tid & 1) * 16;
    const int akey = (arow >> 1) & 3;                       // A ds_write swizzle key
    const long grow = row0 + arow;
    // dead-col liveness: cols >= NR2 have W2=0, bias=0; colb==2 wn==64 wave has
    // ALL cols dead (320-383) -> skips all MFMA/B-reads but keeps barriers+A-prep
    bool nlive[4];
#pragma unroll
    for (int ni = 0; ni < 4; ni++) nlive[ni] = (int)col0 + wn + ni * 16 < NR2;
    __syncthreads();     // sSc/sSh visible

    for (int k0 = 0; k0 < K2E; k0 += 32) {   // K2E=608: z1 cols 608-639 are all 0
#pragma unroll
        for (int i = 0; i < 2; i++) {
            int r = wave * 32 + i * 16;
            if ((int)col0 + r < NR2) {   // B rows beyond NR2 never read
                const unsigned short* gbh = Whi + (col0 + r + sr) * (long)K2 + k0 + scb;
                const unsigned short* gbl = Wlo + (col0 + r + sr) * (long)K2 + k0 + scb;
                __builtin_amdgcn_global_load_lds((const __attribute__((address_space(1))) void*)gbh,
                                                 (__attribute__((address_space(3))) void*)(Bh + r * 32), 16, 0, 0);
                __builtin_amdgcn_global_load_lds((const __attribute__((address_space(1))) void*)gbl,
                                                 (__attribute__((address_space(3))) void*)(Bl + r * 32), 16, 0, 0);
            }
        }
#pragma unroll
        for (int j = 0; j < 4; j++) {
            int cc = k0 + acb + j * 4;                      // logical global col
            ushort4 xv = *(const ushort4*)(z1b + grow * K2 + cc);
            const float4 sc = *(const float4*)(sSc + cc);
            const float4 sh = *(const float4*)(sSh + cc);
            ushort4 hi4, lo4;
            // fmaxf squashes any NaN from stale pad rows (rg>=NN) to 0
            splitbf(fmaxf(bf2f(xv.x) * sc.x + sh.x, 0.f), hi4.x, lo4.x);
            splitbf(fmaxf(bf2f(xv.y) * sc.y + sh.y, 0.f), hi4.y, lo4.y);
            splitbf(fmaxf(bf2f(xv.z) * sc.z + sh.z, 0.f), hi4.z, lo4.z);
            splitbf(fmaxf(bf2f(xv.w) * sc.w + sh.w, 0.f), hi4.w, lo4.w);
            int slog = (acb >> 3) + (j >> 1);               // logical 16B slot 0..3
            int pcol = ((slog ^ akey) << 3) + (j & 1) * 4;  // swizzled LDS col
            *(ushort4*)(Ah + arow * 32 + pcol) = hi4;
            *(ushort4*)(Al + arow * 32 + pcol) = lo4;
        }
        __syncthreads();
        short8 ah[4], alo[4], bh[4], blo[4];
#pragma unroll
        for (int mi = 0; mi < 4; mi++) {
            ah[mi]  = *(const short8*)(Ah + (wm + mi * 16 + fr) * 32 + qs);
            alo[mi] = *(const short8*)(Al + (wm + mi * 16 + fr) * 32 + qs);
        }
#pragma unroll
        for (int ni = 0; ni < 4; ni++) {
            if (nlive[ni]) {
                bh[ni]  = *(const short8*)(Bh + (wn + ni * 16 + fr) * 32 + qs);
                blo[ni] = *(const short8*)(Bl + (wn + ni * 16 + fr) * 32 + qs);
            }
        }
#pragma unroll
        for (int mi = 0; mi < 4; mi++)
#pragma unroll
            for (int ni = 0; ni < 4; ni++) {
                if (nlive[ni]) {
                    acc[mi][ni] = __builtin_amdgcn_mfma_f32_16x16x32_bf16(ah[mi],  bh[ni],  acc[mi][ni], 0, 0, 0);
                    acc[mi][ni] = __builtin_amdgcn_mfma_f32_16x16x32_bf16(alo[mi], bh[ni],  acc[mi][ni], 0, 0, 0);
                    acc[mi][ni] = __builtin_amdgcn_mfma_f32_16x16x32_bf16(ah[mi],  blo[ni], acc[mi][ni], 0, 0, 0);
                }
            }
        __syncthreads();
    }

    if (tid < 128) { ssum[tid] = 0.f; ssq[tid] = 0.f; }
    __syncthreads();
#pragma unroll
    for (int ni = 0; ni < 4; ni++) {
        if (!nlive[ni]) continue;   // dead cols: z2 never written, stats irrelevant
        int cl = wn + ni * 16 + fr;
        long cg = col0 + cl;
        float bs = bias[cg];
        float psum = 0.f, psq = 0.f;
#pragma unroll
        for (int mi = 0; mi < 4; mi++) {
#pragma unroll
            for (int r = 0; r < 4; r++) {
                long rg = row0 + wm + mi * 16 + q * 4 + r;
                float v = acc[mi][ni][r] + bs;
                if (cg < 300) z2f[rg * 300 + cg] = v;
                if (rg < NN) { psum += v; psq += v * v; }
            }
        }
        atomicAdd(&ssum[cl], psum);
        atomicAdd(&ssq[cl], psq);
    }
    __syncthreads();
    if (tid < 128) {
        atomicAdd(&stat_sum[col0 + tid], ssum[tid]);
        atomicAdd(&stat_sq[col0 + tid], ssq[tid]);
    }
}

// ---------------- BN finalize ----------------
__global__ void bn_finalize(const float* __restrict__ sum, const float* __restrict__ sq,
                            const float* __restrict__ g, const float* __restrict__ be,
                            float* __restrict__ scale, float* __restrict__ shift, int n) {
    int c = blockIdx.x * blockDim.x + threadIdx.x;
    if (c >= n) return;
    const float invN = 1.f / (float)NN;
    float mu  = sum[c] * invN;
    float var = sq[c] * invN - mu * mu;
    float rs  = rsqrtf(var + BN_EPS);
    float s   = rs * g[c];               // pad cols: g=0 -> s=0
    scale[c] = s;
    shift[c] = be[c] - mu * s;
}

// ---------------- final BN (last layer only, no relu) -> f32 out ----------------
__global__ void bn2_out(const float* __restrict__ z2,
                        const float* __restrict__ scale, const float* __restrict__ shift,
                        float* __restrict__ out, int do_relu) {
    int idx = blockIdx.x * blockDim.x + threadIdx.x;
    if (idx >= NN * 75) return;
    int n = idx / 75;
    int c = (idx % 75) * 4;
    const float4 v  = *(const float4*)(z2 + (long)n * 300 + c);
    const float4 sc = *(const float4*)(scale + c);
    const float4 sh = *(const float4*)(shift + c);
    float4 o;
    o.x = v.x * sc.x + sh.x;
    o.y = v.y * sc.y + sh.y;
    o.z = v.z * sc.z + sh.z;
    o.w = v.w * sc.w + sh.w;
    if (do_relu) {
        o.x = fmaxf(o.x, 0.f); o.y = fmaxf(o.y, 0.f);
        o.z = fmaxf(o.z, 0.f); o.w = fmaxf(o.w, 0.f);
    }
    *(float4*)(out + (long)n * 300 + c) = o;
}

extern "C" void kernel_launch(void* const* d_in, const int* in_sizes, int n_in,
                              void* d_out, int out_size, void* d_ws, size_t ws_size,
                              hipStream_t stream) {
    const int*   xf   = (const int*)d_in[0];
    const int*   ei   = (const int*)d_in[1];
    const int*   ea   = (const int*)d_in[2];
    const float* atab = (const float*)d_in[3];
    const float* btab = (const float*)d_in[4];
    const float* eps  = (const float*)d_in[5];
    const float* W1   = (const float*)d_in[6];
    const float* b1   = (const float*)d_in[7];
    const float* g1   = (const float*)d_in[8];
    const float* be1  = (const float*)d_in[9];
    const float* W2   = (const float*)d_in[10];
    const float* b2   = (const float*)d_in[11];
    const float* g2   = (const float*)d_in[12];
    const float* be2  = (const float*)d_in[13];
    float* hbuf = (float*)d_out;                 // atom-enc h (layer 0 input); final output

    char* ws = (char*)d_ws;
    size_t off = 0;
    auto alloc = [&](size_t bytes) { size_t o = off; off += (bytes + 255) & ~(size_t)255; return o; };
    // Two 128.1MB rotation regions: zin(l)->R[l&1], z1b(l)->R[1-(l&1)], z2(l)->R[l&1].
    char* R0c = ws + alloc((size_t)MPAD * 640 * 2);
    char* R1c = ws + alloc((size_t)MPAD * 640 * 2);
    unsigned short* W1hi = (unsigned short*)(ws + alloc((size_t)NL * N1 * K1 * 2));
    unsigned short* W1lo = (unsigned short*)(ws + alloc((size_t)NL * N1 * K1 * 2));
    unsigned short* W2hi = (unsigned short*)(ws + alloc((size_t)NL * N2 * K2 * 2));
    unsigned short* W2lo = (unsigned short*)(ws + alloc((size_t)NL * N2 * K2 * 2));
    float* b1p  = (float*)(ws + alloc((size_t)NL * N1 * 4));
    float* g1p  = (float*)(ws + alloc((size_t)NL * N1 * 4));
    float* be1p = (float*)(ws + alloc((size_t)NL * N1 * 4));
    float* b2p  = (float*)(ws + alloc((size_t)NL * N2 * 4));
    float* g2p  = (float*)(ws + alloc((size_t)NL * N2 * 4));
    float* be2p = (float*)(ws + alloc((size_t)NL * N2 * 4));
    float* sums = (float*)(ws + alloc(2048 * 4));    // sum1[640] sq1[640] sum2[384] sq2[384]
    float* scale1 = (float*)(ws + alloc(N1 * 4));
    float* shift1 = (float*)(ws + alloc(N1 * 4));
    float* scale2 = (float*)(ws + alloc(N2 * 4));
    float* shift2 = (float*)(ws + alloc(N2 * 4));
    int* deg     = (int*)(ws + alloc((size_t)NN * 4));
    int* fillc   = (int*)(ws + alloc((size_t)NN * 4));
    int* rowptr  = (int*)(ws + alloc((size_t)(NN + 1) * 4));
    int* csr_src = (int*)(ws + alloc((size_t)NE * 4));
    int* csr_att = (int*)(ws + alloc((size_t)NE * 4));
    int* bsum    = (int*)(ws + alloc((size_t)NB_SCAN * 4));
    (void)ws_size; (void)in_sizes; (void)n_in; (void)out_size;
    // total ws: ~266 MB

    // ---- one-time prep ----
    prep_w1<<<(NL * N1 * K1 + 255) / 256, 256, 0, stream>>>(W1, W1hi, W1lo);
    prep_w2<<<(NL * N2 * K2 + 255) / 256, 256, 0, stream>>>(W2, W2hi, W2lo);
    prep_vec<<<(NL * N1 + 255) / 256, 256, 0, stream>>>(b1, g1, be1, b2, g2, be2,
                                                        b1p, g1p, be1p, b2p, g2p, be2p);
    atom_enc<<<(NN * 75 + 255) / 256, 256, 0, stream>>>(xf, atab, hbuf);
    // CSR build
    hipMemsetAsync(deg, 0, (size_t)NN * 4, stream);
    hipMemsetAsync(fillc, 0, (size_t)NN * 4, stream);
    count_deg<<<(NE + 255) / 256, 256, 0, stream>>>(ei, deg);
    block_deg_sum<<<NB_SCAN, 1024, 0, stream>>>(deg, bsum);
    scan_rowptr2<<<NB_SCAN, 1024, 0, stream>>>(deg, bsum, rowptr);
    fill_csr<<<(NE + 255) / 256, 256, 0, stream>>>(ei, ea, rowptr, fillc, csr_src, csr_att);

    for (int l = 0; l < NL; l++) {
        char* Ra = (l & 1) ? R1c : R0c;       // zin(l) and z2(l)
        char* Rb = (l & 1) ? R0c : R1c;       // z1b(l); holds z2(l-1) before gemm1
        unsigned short* zin = (unsigned short*)Ra;
        unsigned short* z1b = (unsigned short*)Rb;
        float*          z2f = (float*)Ra;
        const float*    z2p = (const float*)Rb;   // z2 of layer l-1

        hipMemsetAsync(sums, 0, 2048 * 4, stream);
        gather_zin<<<(NN * 80 + 255) / 256, 256, 0, stream>>>(
            (l == 0) ? hbuf : z2p, scale2, shift2, (l == 0) ? 0 : 1,
            rowptr, csr_src, csr_att, btab + (size_t)l * 5400, eps, l, zin);
        gemm1_pre<<<G1, 256, 0, stream>>>(
            zin, W1hi + (size_t)l * N1 * K1, W1lo + (size_t)l * N1 * K1,
            b1p + l * N1, z1b, sums + 0, sums + 640);
        bn_finalize<<<(N1 + 255) / 256, 256, 0, stream>>>(sums + 0, sums + 640,
            g1p + l * N1, be1p + l * N1, scale1, shift1, N1);
        gemm2_fused<<<G2, 256, 0, stream>>>(
            z1b, scale1, shift1, W2hi + (size_t)l * N2 * K2, W2lo + (size_t)l * N2 * K2,
            b2p + l * N2, z2f, sums + 1280, sums + 1664);
        bn_finalize<<<(N2 + 255) / 256, 256, 0, stream>>>(sums + 1280, sums + 1664,
            g2p + l * N2, be2p + l * N2, scale2, shift2, N2);
    }
    // final BN (layer NL-1, no relu) -> d_out.  z2(NL-1) lives in R[(NL-1)&1] = R0.
    bn2_out<<<(NN * 75 + 255) / 256, 256, 0, stream>>>(
        (const float*)R0c, scale2, shift2, hbuf, 0);
}

// Round 7
// 2229.350 us; speedup vs baseline: 2.2249x; 2.2249x over previous
//
#include <hip/hip_runtime.h>

#define NL    5
#define NN    100000
#define NE    200000
#define MPAD  100096       // 782 * 128
#define MTILES 782
#define K1    320          // EMB 300 padded
#define N1    640          // 600 padded
#define K2    640          // z1b row stride
#define K2E   608          // effective K for gemm2: z1 cols 608-639 are exactly 0 and W2 pads are 0
#define N2    384          // 300 padded
#define BN_EPS 1e-5f
#define G1    (MTILES * 5) // gemm1 grid (5 col-tiles)
#define G2    (MTILES * 3) // gemm2 grid (3 col-tiles)
#define NB_SCAN 98         // (NN + 1023) / 1024

typedef __attribute__((ext_vector_type(8))) short   short8;
typedef __attribute__((ext_vector_type(4))) float   floatx4;

// exact hi/lo bf16 split: x == bf(hi) + bf(lo) + O(2^-17 |x|)
__device__ inline void splitbf(float x, unsigned short& hi, unsigned short& lo) {
    unsigned u = __float_as_uint(x);
    unsigned hb = u & 0xFFFF0000u;
    float lf = x - __uint_as_float(hb);     // exact (shares leading bits)
    hi = (unsigned short)(u >> 16);
    lo = (unsigned short)(__float_as_uint(lf) >> 16);
}
__device__ inline unsigned short f2bf(float f) {
    unsigned u = __float_as_uint(f);
    unsigned r = u + 0x7FFFu + ((u >> 16) & 1u);   // RNE
    return (unsigned short)(r >> 16);
}
__device__ inline float bf2f(unsigned short b) {
    return __uint_as_float(((unsigned)b) << 16);
}

// XCD-contiguous swizzle
__device__ inline void swz(int id, int G, int NC, int& row, int& col) {
    int q = G >> 3, r = G & 7;
    int x = id & 7, k = id >> 3;
    int w = x * q + (x < r ? x : r) + k;
    row = w / NC; col = w % NC;
}

// ---------------- weight prep: hi/lo planes, n-major, padded ----------------
__global__ void prep_w1(const float* __restrict__ W1,
                        unsigned short* __restrict__ Whi, unsigned short* __restrict__ Wlo) {
    int idx = blockIdx.x * blockDim.x + threadIdx.x;
    if (idx >= NL * N1 * K1) return;                // [l][n<640][k<320]
    int l = idx / (N1 * K1);
    int rem = idx % (N1 * K1);
    int n = rem / K1;
    int k = rem % K1;
    float v = (k < 300 && n < 600) ? W1[((long)l * 300 + k) * 600 + n] : 0.f;
    unsigned short hi, lo; splitbf(v, hi, lo);
    Whi[idx] = hi; Wlo[idx] = lo;
}

__global__ void prep_w2(const float* __restrict__ W2,
                        unsigned short* __restrict__ Whi, unsigned short* __restrict__ Wlo) {
    int idx = blockIdx.x * blockDim.x + threadIdx.x;
    if (idx >= NL * N2 * K2) return;                // [l][d<384][k<640]
    int l = idx / (N2 * K2);
    int rem = idx % (N2 * K2);
    int d = rem / K2;
    int k = rem % K2;
    float v = (d < 300 && k < 600) ? W2[((long)l * 600 + k) * 300 + d] : 0.f;
    unsigned short hi, lo; splitbf(v, hi, lo);
    Whi[idx] = hi; Wlo[idx] = lo;
}

__global__ void prep_vec(const float* __restrict__ b1, const float* __restrict__ g1, const float* __restrict__ be1,
                         const float* __restrict__ b2, const float* __restrict__ g2, const float* __restrict__ be2,
                         float* __restrict__ b1p, float* __restrict__ g1p, float* __restrict__ be1p,
                         float* __restrict__ b2p, float* __restrict__ g2p, float* __restrict__ be2p) {
    int idx = blockIdx.x * blockDim.x + threadIdx.x;
    if (idx < NL * N1) {
        int l = idx / N1, n = idx % N1;
        bool ok = (n < 600);
        b1p[idx]  = ok ? b1[l * 600 + n]  : 0.f;
        g1p[idx]  = ok ? g1[l * 600 + n]  : 0.f;
        be1p[idx] = ok ? be1[l * 600 + n] : 0.f;
    }
    if (idx < NL * N2) {
        int l = idx / N2, d = idx % N2;
        bool ok = (d < 300);
        b2p[idx]  = ok ? b2[l * 300 + d]  : 0.f;
        g2p[idx]  = ok ? g2[l * 300 + d]  : 0.f;
        be2p[idx] = ok ? be2[l * 300 + d] : 0.f;
    }
}

// ---------------- atom encoder ----------------
__global__ void atom_enc(const int* __restrict__ xf, const float* __restrict__ tab,
                         float* __restrict__ h) {
    int idx = blockIdx.x * blockDim.x + threadIdx.x;
    if (idx >= NN * 75) return;
    int n = idx / 75;
    int c = (idx % 75) * 4;
    float4 s = make_float4(0.f, 0.f, 0.f, 0.f);
#pragma unroll
    for (int f = 0; f < 9; f++) {
        int v = xf[n * 9 + f];
        const float4 t = *(const float4*)(tab + (long)(f * 119 + v) * 300 + c);
        s.x += t.x; s.y += t.y; s.z += t.z; s.w += t.w;
    }
    *(float4*)(h + (long)n * 300 + c) = s;
}

// ---------------- CSR build ----------------
__global__ void count_deg(const int* __restrict__ ei, int* __restrict__ deg) {
    int e = blockIdx.x * blockDim.x + threadIdx.x;
    if (e >= NE) return;
    atomicAdd(&deg[ei[NE + e]], 1);
}

__global__ void block_deg_sum(const int* __restrict__ deg, int* __restrict__ bsum) {
    __shared__ int tmp[1024];
    const int t = threadIdx.x;
    const int idx = blockIdx.x * 1024 + t;
    tmp[t] = (idx < NN) ? deg[idx] : 0;
    __syncthreads();
    for (int o = 512; o > 0; o >>= 1) {
        if (t < o) tmp[t] += tmp[t + o];
        __syncthreads();
    }
    if (t == 0) bsum[blockIdx.x] = tmp[0];
}

__global__ void scan_rowptr2(const int* __restrict__ deg, const int* __restrict__ bsum,
                             int* __restrict__ rowptr) {
    __shared__ int tmp[1024];
    __shared__ int sbase;
    const int b = blockIdx.x;
    const int t = threadIdx.x;
    tmp[t] = (t < b) ? bsum[t] : 0;          // NB_SCAN <= 1024
    __syncthreads();
    for (int o = 512; o > 0; o >>= 1) {
        if (t < o) tmp[t] += tmp[t + o];
        __syncthreads();
    }
    if (t == 0) sbase = tmp[0];
    __syncthreads();
    const int base = sbase;
    const int idx = b * 1024 + t;
    const int d = (idx < NN) ? deg[idx] : 0;
    tmp[t] = d;
    __syncthreads();
    for (int o = 1; o < 1024; o <<= 1) {
        int u = (t >= o) ? tmp[t - o] : 0;
        __syncthreads();
        tmp[t] += u;
        __syncthreads();
    }
    if (idx < NN) rowptr[idx] = base + tmp[t] - d;   // exclusive prefix
    if (idx == NN - 1) rowptr[NN] = base + tmp[t];   // total edge count
}

__global__ void fill_csr(const int* __restrict__ ei, const int* __restrict__ ea,
                         const int* __restrict__ rowptr, int* __restrict__ fillc,
                         int* __restrict__ csr_src, int* __restrict__ csr_att) {
    int e = blockIdx.x * blockDim.x + threadIdx.x;
    if (e >= NE) return;
    int dst = ei[NE + e];
    int pos = atomicAdd(&fillc[dst], 1);
    int slot = rowptr[dst] + pos;
    csr_src[slot] = ei[e];
    csr_att[slot] = ea[e * 3] | (ea[e * 3 + 1] << 3) | (ea[e * 3 + 2] << 6);
}

// ---- gather + GIN combine + exact split, BN2+ReLU of previous layer folded in.
__global__ void gather_zin(const float* __restrict__ hsrc,
                           const float* __restrict__ sc2v, const float* __restrict__ sh2v,
                           int use_bn,
                           const int* __restrict__ rowptr,
                           const int* __restrict__ csr_src, const int* __restrict__ csr_att,
                           const float* __restrict__ bond,
                           const float* __restrict__ eps, int l,
                           unsigned short* __restrict__ zin) {
    int idx = blockIdx.x * blockDim.x + threadIdx.x;
    if (idx >= NN * 80) return;
    int n = idx / 80;
    int c = (idx % 80) * 4;
    ushort4 hi4, lo4;
    if (c < 300) {
        float4 sc = make_float4(1.f, 1.f, 1.f, 1.f);
        float4 sh = make_float4(0.f, 0.f, 0.f, 0.f);
        if (use_bn) {
            sc = *(const float4*)(sc2v + c);
            sh = *(const float4*)(sh2v + c);
        }
        int p0 = rowptr[n], p1 = rowptr[n + 1];
        float4 s = make_float4(0.f, 0.f, 0.f, 0.f);
        for (int j = p0; j < p1; j++) {
            int src = csr_src[j];
            int att = csr_att[j];
            float4 hv = *(const float4*)(hsrc + (long)src * 300 + c);
            if (use_bn) {
                hv.x = fmaxf(hv.x * sc.x + sh.x, 0.f);
                hv.y = fmaxf(hv.y * sc.y + sh.y, 0.f);
                hv.z = fmaxf(hv.z * sc.z + sh.z, 0.f);
                hv.w = fmaxf(hv.w * sc.w + sh.w, 0.f);
            }
            const float4 t0 = *(const float4*)(bond + (0 * 6 + (att & 7)) * 300 + c);
            const float4 t1 = *(const float4*)(bond + (1 * 6 + ((att >> 3) & 7)) * 300 + c);
            const float4 t2 = *(const float4*)(bond + (2 * 6 + ((att >> 6) & 1)) * 300 + c);
            float m;
            m = hv.x + t0.x + t1.x + t2.x; s.x += (m > 0.f ? m : 0.f);
            m = hv.y + t0.y + t1.y + t2.y; s.y += (m > 0.f ? m : 0.f);
            m = hv.z + t0.z + t1.z + t2.z; s.z += (m > 0.f ? m : 0.f);
            m = hv.w + t0.w + t1.w + t2.w; s.w += (m > 0.f ? m : 0.f);
        }
        const float ep = 1.f + eps[l];
        float4 hn = *(const float4*)(hsrc + (long)n * 300 + c);
        if (use_bn) {
            hn.x = fmaxf(hn.x * sc.x + sh.x, 0.f);
            hn.y = fmaxf(hn.y * sc.y + sh.y, 0.f);
            hn.z = fmaxf(hn.z * sc.z + sh.z, 0.f);
            hn.w = fmaxf(hn.w * sc.w + sh.w, 0.f);
        }
        splitbf(ep * hn.x + s.x, hi4.x, lo4.x);
        splitbf(ep * hn.y + s.y, hi4.y, lo4.y);
        splitbf(ep * hn.z + s.z, hi4.z, lo4.z);
        splitbf(ep * hn.w + s.w, hi4.w, lo4.w);
    } else {
        hi4.x = hi4.y = hi4.z = hi4.w = 0;
        lo4.x = lo4.y = lo4.z = lo4.w = 0;
    }
    *(ushort4*)(zin + (long)n * 640 + c)       = hi4;
    *(ushort4*)(zin + (long)n * 640 + 320 + c) = lo4;
}

// LDS bank-conflict swizzle (rule 21: linear gload_lds dest + inverse-swizzled
// global SOURCE + swizzled READ). Physical 16B slot = logical slot ^ ((row>>1)&3).
// R5 lesson: 128x64 wave tile regressed (occupancy 3->2 blocks/CU). R6 lesson:
// dead-column guards exploded HBM traffic 8x (partial-line writes / broken
// streaming) -> GEMMs restored to the verified R4 structure, unconditional
// staging, dense writes.  Only surviving R6 idea: gemm2 K-loop to K2E=608
// (dropped k-steps multiply exact zeros on both operands; output bitwise same).

// ---------------- GEMM1: z1 = zin @ W1 + b1 (split-exact, pre-split A) ----------------
__global__ __launch_bounds__(256, 4)
void gemm1_pre(const unsigned short* __restrict__ zin,
               const unsigned short* __restrict__ Whi, const unsigned short* __restrict__ Wlo,
               const float* __restrict__ bias, unsigned short* __restrict__ z1b,
               float* __restrict__ stat_sum, float* __restrict__ stat_sq) {
    __shared__ unsigned short Ah[128 * 32], Al[128 * 32];
    __shared__ unsigned short Bh[128 * 32], Bl[128 * 32];
    __shared__ float ssum[128], ssq[128];

    const int tid  = threadIdx.x;
    const int wave = tid >> 6;
    const int lane = tid & 63;
    int rowb, colb; swz(blockIdx.x, G1, 5, rowb, colb);
    const long row0 = (long)rowb * 128;
    const long col0 = (long)colb * 128;

    floatx4 acc[4][4];
#pragma unroll
    for (int mi = 0; mi < 4; mi++)
#pragma unroll
        for (int ni = 0; ni < 4; ni++)
            acc[mi][ni] = (floatx4){0.f, 0.f, 0.f, 0.f};

    const int sr  = lane >> 2;
    const int scb = (((lane & 3) ^ ((sr >> 1) & 3))) * 8;  // pre-swizzled source slot
    const int wm  = (wave >> 1) * 64;
    const int wn  = (wave & 1) * 64;
    const int fr  = lane & 15;
    const int q   = lane >> 4;
    const int qs  = (q ^ ((fr >> 1) & 3)) * 8;             // swizzled read slot

    for (int k0 = 0; k0 < K1; k0 += 32) {
#pragma unroll
        for (int i = 0; i < 2; i++) {
            int r = wave * 32 + i * 16;
            const unsigned short* gah = zin + (row0 + r + sr) * 640 + k0 + scb;
            const unsigned short* gbh = Whi + (col0 + r + sr) * (long)K1 + k0 + scb;
            const unsigned short* gbl = Wlo + (col0 + r + sr) * (long)K1 + k0 + scb;
            __builtin_amdgcn_global_load_lds((const __attribute__((address_space(1))) void*)gah,
                                             (__attribute__((address_space(3))) void*)(Ah + r * 32), 16, 0, 0);
            __builtin_amdgcn_global_load_lds((const __attribute__((address_space(1))) void*)(gah + 320),
                                             (__attribute__((address_space(3))) void*)(Al + r * 32), 16, 0, 0);
            __builtin_amdgcn_global_load_lds((const __attribute__((address_space(1))) void*)gbh,
                                             (__attribute__((address_space(3))) void*)(Bh + r * 32), 16, 0, 0);
            __builtin_amdgcn_global_load_lds((const __attribute__((address_space(1))) void*)gbl,
                                             (__attribute__((address_space(3))) void*)(Bl + r * 32), 16, 0, 0);
        }
        __syncthreads();
        short8 ah[4], alo[4], bh[4], blo[4];
#pragma unroll
        for (int mi = 0; mi < 4; mi++) {
            ah[mi]  = *(const short8*)(Ah + (wm + mi * 16 + fr) * 32 + qs);
            alo[mi] = *(const short8*)(Al + (wm + mi * 16 + fr) * 32 + qs);
        }
#pragma unroll
        for (int ni = 0; ni < 4; ni++) {
            bh[ni]  = *(const short8*)(Bh + (wn + ni * 16 + fr) * 32 + qs);
            blo[ni] = *(const short8*)(Bl + (wn + ni * 16 + fr) * 32 + qs);
        }
#pragma unroll
        for (int mi = 0; mi < 4; mi++)
#pragma unroll
            for (int ni = 0; ni < 4; ni++) {
                acc[mi][ni] = __builtin_amdgcn_mfma_f32_16x16x32_bf16(ah[mi],  bh[ni],  acc[mi][ni], 0, 0, 0);
                acc[mi][ni] = __builtin_amdgcn_mfma_f32_16x16x32_bf16(alo[mi], bh[ni],  acc[mi][ni], 0, 0, 0);
                acc[mi][ni] = __builtin_amdgcn_mfma_f32_16x16x32_bf16(ah[mi],  blo[ni], acc[mi][ni], 0, 0, 0);
            }
        __syncthreads();
    }

    if (tid < 128) { ssum[tid] = 0.f; ssq[tid] = 0.f; }
    __syncthreads();
#pragma unroll
    for (int ni = 0; ni < 4; ni++) {
        int cl = wn + ni * 16 + fr;
        long cg = col0 + cl;
        float bs = bias[cg];
        float psum = 0.f, psq = 0.f;
#pragma unroll
        for (int mi = 0; mi < 4; mi++) {
#pragma unroll
            for (int r = 0; r < 4; r++) {
                long rg = row0 + wm + mi * 16 + q * 4 + r;
                float v = acc[mi][ni][r] + bs;
                z1b[rg * N1 + cg] = f2bf(v);
                if (rg < NN) { psum += v; psq += v * v; }
            }
        }
        atomicAdd(&ssum[cl], psum);
        atomicAdd(&ssq[cl], psq);
    }
    __syncthreads();
    if (tid < 128) {
        atomicAdd(&stat_sum[col0 + tid], ssum[tid]);
        atomicAdd(&stat_sq[col0 + tid], ssq[tid]);
    }
}

// ---------------- GEMM2 fused: z2 = relu(BN(z1)) @ W2 + b2 ----------------
__global__ __launch_bounds__(256, 4)
void gemm2_fused(const unsigned short* __restrict__ z1b,
                 const float* __restrict__ scale, const float* __restrict__ shift,
                 const unsigned short* __restrict__ Whi, const unsigned short* __restrict__ Wlo,
                 const float* __restrict__ bias, float* __restrict__ z2f,
                 float* __restrict__ stat_sum, float* __restrict__ stat_sq) {
    __shared__ unsigned short Ah[128 * 32], Al[128 * 32];
    __shared__ unsigned short Bh[128 * 32], Bl[128 * 32];
    __shared__ float sSc[K2], sSh[K2];
    __shared__ float ssum[128], ssq[128];

    const int tid  = threadIdx.x;
    const int wave = tid >> 6;
    const int lane = tid & 63;
    int rowb, colb; swz(blockIdx.x, G2, 3, rowb, colb);
    const long row0 = (long)rowb * 128;
    const long col0 = (long)colb * 128;

    for (int i = tid; i < K2; i += 256) { sSc[i] = scale[i]; sSh[i] = shift[i]; }

    floatx4 acc[4][4];
#pragma unroll
    for (int mi = 0; mi < 4; mi++)
#pragma unroll
        for (int ni = 0; ni < 4; ni++)
            acc[mi][ni] = (floatx4){0.f, 0.f, 0.f, 0.f};

    const int sr  = lane >> 2;
    const int scb = (((lane & 3) ^ ((sr >> 1) & 3))) * 8;   // pre-swizzled source slot
    const int wm  = (wave >> 1) * 64;
    const int wn  = (wave & 1) * 64;
    const int fr  = lane & 15;
    const int q   = lane >> 4;
    const int qs  = (q ^ ((fr >> 1) & 3)) * 8;              // swizzled read slot
    const int arow = tid >> 1;
    const int acb  = (tid & 1) * 16;
    const int akey = (arow >> 1) & 3;                       // A ds_write swizzle key
    const long grow = row0 + arow;
    __syncthreads();     // sSc/sSh visible

    for (int k0 = 0; k0 < K2E; k0 += 32) {   // K2E=608: k-steps beyond multiply exact zeros
#pragma unroll
        for (int i = 0; i < 2; i++) {
            int r = wave * 32 + i * 16;
            const unsigned short* gbh = Whi + (col0 + r + sr) * (long)K2 + k0 + scb;
            const unsigned short* gbl = Wlo + (col0 + r + sr) * (long)K2 + k0 + scb;
            __builtin_amdgcn_global_load_lds((const __attribute__((address_space(1))) void*)gbh,
                                             (__attribute__((address_space(3))) void*)(Bh + r * 32), 16, 0, 0);
            __builtin_amdgcn_global_load_lds((const __attribute__((address_space(1))) void*)gbl,
                                             (__attribute__((address_space(3))) void*)(Bl + r * 32), 16, 0, 0);
        }
#pragma unroll
        for (int j = 0; j < 4; j++) {
            int cc = k0 + acb + j * 4;                      // logical global col
            ushort4 xv = *(const ushort4*)(z1b + grow * K2 + cc);
            const float4 sc = *(const float4*)(sSc + cc);
            const float4 sh = *(const float4*)(sSh + cc);
            ushort4 hi4, lo4;
            // fmaxf squashes any NaN from stale pad rows (rg>=NN) to 0
            splitbf(fmaxf(bf2f(xv.x) * sc.x + sh.x, 0.f), hi4.x, lo4.x);
            splitbf(fmaxf(bf2f(xv.y) * sc.y + sh.y, 0.f), hi4.y, lo4.y);
            splitbf(fmaxf(bf2f(xv.z) * sc.z + sh.z, 0.f), hi4.z, lo4.z);
            splitbf(fmaxf(bf2f(xv.w) * sc.w + sh.w, 0.f), hi4.w, lo4.w);
            int slog = (acb >> 3) + (j >> 1);               // logical 16B slot 0..3
            int pcol = ((slog ^ akey) << 3) + (j & 1) * 4;  // swizzled LDS col
            *(ushort4*)(Ah + arow * 32 + pcol) = hi4;
            *(ushort4*)(Al + arow * 32 + pcol) = lo4;
        }
        __syncthreads();
        short8 ah[4], alo[4], bh[4], blo[4];
#pragma unroll
        for (int mi = 0; mi < 4; mi++) {
            ah[mi]  = *(const short8*)(Ah + (wm + mi * 16 + fr) * 32 + qs);
            alo[mi] = *(const short8*)(Al + (wm + mi * 16 + fr) * 32 + qs);
        }
#pragma unroll
        for (int ni = 0; ni < 4; ni++) {
            bh[ni]  = *(const short8*)(Bh + (wn + ni * 16 + fr) * 32 + qs);
            blo[ni] = *(const short8*)(Bl + (wn + ni * 16 + fr) * 32 + qs);
        }
#pragma unroll
        for (int mi = 0; mi < 4; mi++)
#pragma unroll
            for (int ni = 0; ni < 4; ni++) {
                acc[mi][ni] = __builtin_amdgcn_mfma_f32_16x16x32_bf16(ah[mi],  bh[ni],  acc[mi][ni], 0, 0, 0);
                acc[mi][ni] = __builtin_amdgcn_mfma_f32_16x16x32_bf16(alo[mi], bh[ni],  acc[mi][ni], 0, 0, 0);
                acc[mi][ni] = __builtin_amdgcn_mfma_f32_16x16x32_bf16(ah[mi],  blo[ni], acc[mi][ni], 0, 0, 0);
            }
        __syncthreads();
    }

    if (tid < 128) { ssum[tid] = 0.f; ssq[tid] = 0.f; }
    __syncthreads();
#pragma unroll
    for (int ni = 0; ni < 4; ni++) {
        int cl = wn + ni * 16 + fr;
        long cg = col0 + cl;
        float bs = bias[cg];
        float psum = 0.f, psq = 0.f;
#pragma unroll
        for (int mi = 0; mi < 4; mi++) {
#pragma unroll
            for (int r = 0; r < 4; r++) {
                long rg = row0 + wm + mi * 16 + q * 4 + r;
                float v = acc[mi][ni][r] + bs;
                if (cg < 300) z2f[rg * 300 + cg] = v;
                if (rg < NN) { psum += v; psq += v * v; }
            }
        }
        atomicAdd(&ssum[cl], psum);
        atomicAdd(&ssq[cl], psq);
    }
    __syncthreads();
    if (tid < 128) {
        atomicAdd(&stat_sum[col0 + tid], ssum[tid]);
        atomicAdd(&stat_sq[col0 + tid], ssq[tid]);
    }
}

// ---------------- BN finalize ----------------
__global__ void bn_finalize(const float* __restrict__ sum, const float* __restrict__ sq,
                            const float* __restrict__ g, const float* __restrict__ be,
                            float* __restrict__ scale, float* __restrict__ shift, int n) {
    int c = blockIdx.x * blockDim.x + threadIdx.x;
    if (c >= n) return;
    const float invN = 1.f / (float)NN;
    float mu  = sum[c] * invN;
    float var = sq[c] * invN - mu * mu;
    float rs  = rsqrtf(var + BN_EPS);
    float s   = rs * g[c];               // pad cols: g=0 -> s=0
    scale[c] = s;
    shift[c] = be[c] - mu * s;
}

// ---------------- final BN (last layer only, no relu) -> f32 out ----------------
__global__ void bn2_out(const float* __restrict__ z2,
                        const float* __restrict__ scale, const float* __restrict__ shift,
                        float* __restrict__ out, int do_relu) {
    int idx = blockIdx.x * blockDim.x + threadIdx.x;
    if (idx >= NN * 75) return;
    int n = idx / 75;
    int c = (idx % 75) * 4;
    const float4 v  = *(const float4*)(z2 + (long)n * 300 + c);
    const float4 sc = *(const float4*)(scale + c);
    const float4 sh = *(const float4*)(shift + c);
    float4 o;
    o.x = v.x * sc.x + sh.x;
    o.y = v.y * sc.y + sh.y;
    o.z = v.z * sc.z + sh.z;
    o.w = v.w * sc.w + sh.w;
    if (do_relu) {
        o.x = fmaxf(o.x, 0.f); o.y = fmaxf(o.y, 0.f);
        o.z = fmaxf(o.z, 0.f); o.w = fmaxf(o.w, 0.f);
    }
    *(float4*)(out + (long)n * 300 + c) = o;
}

extern "C" void kernel_launch(void* const* d_in, const int* in_sizes, int n_in,
                              void* d_out, int out_size, void* d_ws, size_t ws_size,
                              hipStream_t stream) {
    const int*   xf   = (const int*)d_in[0];
    const int*   ei   = (const int*)d_in[1];
    const int*   ea   = (const int*)d_in[2];
    const float* atab = (const float*)d_in[3];
    const float* btab = (const float*)d_in[4];
    const float* eps  = (const float*)d_in[5];
    const float* W1   = (const float*)d_in[6];
    const float* b1   = (const float*)d_in[7];
    const float* g1   = (const float*)d_in[8];
    const float* be1  = (const float*)d_in[9];
    const float* W2   = (const float*)d_in[10];
    const float* b2   = (const float*)d_in[11];
    const float* g2   = (const float*)d_in[12];
    const float* be2  = (const float*)d_in[13];
    float* hbuf = (float*)d_out;                 // atom-enc h (layer 0 input); final output

    char* ws = (char*)d_ws;
    size_t off = 0;
    auto alloc = [&](size_t bytes) { size_t o = off; off += (bytes + 255) & ~(size_t)255; return o; };
    // Two 128.1MB rotation regions: zin(l)->R[l&1], z1b(l)->R[1-(l&1)], z2(l)->R[l&1].
    char* R0c = ws + alloc((size_t)MPAD * 640 * 2);
    char* R1c = ws + alloc((size_t)MPAD * 640 * 2);
    unsigned short* W1hi = (unsigned short*)(ws + alloc((size_t)NL * N1 * K1 * 2));
    unsigned short* W1lo = (unsigned short*)(ws + alloc((size_t)NL * N1 * K1 * 2));
    unsigned short* W2hi = (unsigned short*)(ws + alloc((size_t)NL * N2 * K2 * 2));
    unsigned short* W2lo = (unsigned short*)(ws + alloc((size_t)NL * N2 * K2 * 2));
    float* b1p  = (float*)(ws + alloc((size_t)NL * N1 * 4));
    float* g1p  = (float*)(ws + alloc((size_t)NL * N1 * 4));
    float* be1p = (float*)(ws + alloc((size_t)NL * N1 * 4));
    float* b2p  = (float*)(ws + alloc((size_t)NL * N2 * 4));
    float* g2p  = (float*)(ws + alloc((size_t)NL * N2 * 4));
    float* be2p = (float*)(ws + alloc((size_t)NL * N2 * 4));
    float* sums = (float*)(ws + alloc(2048 * 4));    // sum1[640] sq1[640] sum2[384] sq2[384]
    float* scale1 = (float*)(ws + alloc(N1 * 4));
    float* shift1 = (float*)(ws + alloc(N1 * 4));
    float* scale2 = (float*)(ws + alloc(N2 * 4));
    float* shift2 = (float*)(ws + alloc(N2 * 4));
    int* deg     = (int*)(ws + alloc((size_t)NN * 4));
    int* fillc   = (int*)(ws + alloc((size_t)NN * 4));
    int* rowptr  = (int*)(ws + alloc((size_t)(NN + 1) * 4));
    int* csr_src = (int*)(ws + alloc((size_t)NE * 4));
    int* csr_att = (int*)(ws + alloc((size_t)NE * 4));
    int* bsum    = (int*)(ws + alloc((size_t)NB_SCAN * 4));
    (void)ws_size; (void)in_sizes; (void)n_in; (void)out_size;
    // total ws: ~266 MB

    // ---- one-time prep ----
    prep_w1<<<(NL * N1 * K1 + 255) / 256, 256, 0, stream>>>(W1, W1hi, W1lo);
    prep_w2<<<(NL * N2 * K2 + 255) / 256, 256, 0, stream>>>(W2, W2hi, W2lo);
    prep_vec<<<(NL * N1 + 255) / 256, 256, 0, stream>>>(b1, g1, be1, b2, g2, be2,
                                                        b1p, g1p, be1p, b2p, g2p, be2p);
    atom_enc<<<(NN * 75 + 255) / 256, 256, 0, stream>>>(xf, atab, hbuf);
    // CSR build
    hipMemsetAsync(deg, 0, (size_t)NN * 4, stream);
    hipMemsetAsync(fillc, 0, (size_t)NN * 4, stream);
    count_deg<<<(NE + 255) / 256, 256, 0, stream>>>(ei, deg);
    block_deg_sum<<<NB_SCAN, 1024, 0, stream>>>(deg, bsum);
    scan_rowptr2<<<NB_SCAN, 1024, 0, stream>>>(deg, bsum, rowptr);
    fill_csr<<<(NE + 255) / 256, 256, 0, stream>>>(ei, ea, rowptr, fillc, csr_src, csr_att);

    for (int l = 0; l < NL; l++) {
        char* Ra = (l & 1) ? R1c : R0c;       // zin(l) and z2(l)
        char* Rb = (l & 1) ? R0c : R1c;       // z1b(l); holds z2(l-1) before gemm1
        unsigned short* zin = (unsigned short*)Ra;
        unsigned short* z1b = (unsigned short*)Rb;
        float*          z2f = (float*)Ra;
        const float*    z2p = (const float*)Rb;   // z2 of layer l-1

        hipMemsetAsync(sums, 0, 2048 * 4, stream);
        gather_zin<<<(NN * 80 + 255) / 256, 256, 0, stream>>>(
            (l == 0) ? hbuf : z2p, scale2, shift2, (l == 0) ? 0 : 1,
            rowptr, csr_src, csr_att, btab + (size_t)l * 5400, eps, l, zin);
        gemm1_pre<<<G1, 256, 0, stream>>>(
            zin, W1hi + (size_t)l * N1 * K1, W1lo + (size_t)l * N1 * K1,
            b1p + l * N1, z1b, sums + 0, sums + 640);
        bn_finalize<<<(N1 + 255) / 256, 256, 0, stream>>>(sums + 0, sums + 640,
            g1p + l * N1, be1p + l * N1, scale1, shift1, N1);
        gemm2_fused<<<G2, 256, 0, stream>>>(
            z1b, scale1, shift1, W2hi + (size_t)l * N2 * K2, W2lo + (size_t)l * N2 * K2,
            b2p + l * N2, z2f, sums + 1280, sums + 1664);
        bn_finalize<<<(N2 + 255) / 256, 256, 0, stream>>>(sums + 1280, sums + 1664,
            g2p + l * N2, be2p + l * N2, scale2, shift2, N2);
    }
    // final BN (layer NL-1, no relu) -> d_out.  z2(NL-1) lives in R[(NL-1)&1] = R0.
    bn2_out<<<(NN * 75 + 255) / 256, 256, 0, stream>>>(
        (const float*)R0c, scale2, shift2, hbuf, 0);
}